// Round 3
// baseline (988.337 us; speedup 1.0000x reference)
//
#include <hip/hip_runtime.h>
#include <hip/hip_bf16.h>

typedef unsigned short u16;
typedef unsigned int u32;
typedef __attribute__((ext_vector_type(8))) short bf16x8;
typedef __attribute__((ext_vector_type(4))) float f32x4;

// ---------------------------------------------------------------- helpers
__device__ __forceinline__ u16 f2bf(float f) {
    u32 u = __float_as_uint(f);
    u += 0x7FFFu + ((u >> 16) & 1u);   // RNE
    return (u16)(u >> 16);
}
__device__ __forceinline__ u32 pack2(float a, float b) {
    return (u32)f2bf(a) | ((u32)f2bf(b) << 16);
}

#define GLDS16(gp, lp)                                                          \
    __builtin_amdgcn_global_load_lds(                                           \
        (const __attribute__((address_space(1))) void*)(gp),                    \
        (__attribute__((address_space(3))) void*)(lp), 16, 0, 0)

// ---------------------------------------------------------------- cast fp32 -> bf16
__global__ __launch_bounds__(256) void cast_f32_bf16(const float* __restrict__ src,
                                                     u16* __restrict__ dst, int n8) {
    int stride = gridDim.x * blockDim.x;
    for (int i = blockIdx.x * blockDim.x + threadIdx.x; i < n8; i += stride) {
        const float4* sp = (const float4*)src + (size_t)i * 2;
        float4 a = sp[0], b = sp[1];
        uint4 o;
        o.x = pack2(a.x, a.y);
        o.y = pack2(a.z, a.w);
        o.z = pack2(b.x, b.y);
        o.w = pack2(b.z, b.w);
        ((uint4*)dst)[i] = o;
    }
}

// ---------------------------------------------------------------- GEMM  C = A * B^T (+bias, +fused epilogue)
// A: [z][2048][4096] bf16 row-major (k contiguous), B: [z][4096][4096] bf16 (k contiguous)
// PROJ: out bf16 natural layout with interference mix (+0.125 scale for z==0)
// !PROJ: out fp32 natural layout + bias
// m97-verified structure: 128x128 tile, BK=64, global_load_lds w=16, 2-barrier loop.
template <bool PROJ>
__global__ __launch_bounds__(256) void gemm_bt(
    const u16* __restrict__ Ab, const u16* __restrict__ Bb,
    const float* __restrict__ b0, const float* __restrict__ b1, const float* __restrict__ b2,
    const float* __restrict__ interf, const float* __restrict__ amp,
    u16* __restrict__ Yb, float* __restrict__ Cf) {
    constexpr int M = 2048, N = 4096, K = 4096;
    const int tid = threadIdx.x;
    const int l = tid & 63, w = tid >> 6;
    const int z = PROJ ? blockIdx.z : 0;
    const int n0 = blockIdx.x * 128, m0 = blockIdx.y * 128;
    const u16* A = Ab + (size_t)z * M * K;
    const u16* B = Bb + (size_t)z * N * K;

    __shared__ u16 As[128 * 64];
    __shared__ u16 Bs[128 * 64];
    __shared__ float Ish[256];
    if (PROJ) Ish[tid] = interf[tid];

    const int wr = (w >> 1) * 64, wc = (w & 1) * 64;
    const int fr = l & 15, fg = l >> 4;

    f32x4 acc[4][4] = {};

    int srow[4], scol[4], soff[4];
    #pragma unroll
    for (int r = 0; r < 4; ++r) {
        int e = (r * 4 + w) * 512 + l * 8;   // lds dest = wave-uniform base + lane*16B
        soff[r] = e;
        srow[r] = e >> 6;
        scol[r] = e & 63;
    }

    for (int kt = 0; kt < K; kt += 64) {
        #pragma unroll
        for (int r = 0; r < 4; ++r) {
            GLDS16(A + (size_t)(m0 + srow[r]) * K + kt + scol[r], As + soff[r]);
            GLDS16(B + (size_t)(n0 + srow[r]) * K + kt + scol[r], Bs + soff[r]);
        }
        __syncthreads();
        #pragma unroll
        for (int kb = 0; kb < 2; ++kb) {
            bf16x8 af[4], bfr[4];
            #pragma unroll
            for (int mi = 0; mi < 4; ++mi)
                af[mi] = *(const bf16x8*)&As[(wr + mi * 16 + fr) * 64 + kb * 32 + fg * 8];
            #pragma unroll
            for (int nj = 0; nj < 4; ++nj)
                bfr[nj] = *(const bf16x8*)&Bs[(wc + nj * 16 + fr) * 64 + kb * 32 + fg * 8];
            #pragma unroll
            for (int mi = 0; mi < 4; ++mi)
                #pragma unroll
                for (int nj = 0; nj < 4; ++nj)
                    acc[mi][nj] = __builtin_amdgcn_mfma_f32_16x16x32_bf16(af[mi], bfr[nj],
                                                                          acc[mi][nj], 0, 0, 0);
        }
        __syncthreads();
    }

    if (PROJ) {
        const float camp = 0.1f * amp[0];
        const float* bias = (z == 0) ? b0 : (z == 1) ? b1 : b2;
        const float qs = (z == 0) ? 0.125f : 1.0f;  // fold 1/sqrt(dk) into Q
        #pragma unroll
        for (int nj = 0; nj < 4; ++nj) {
            const int ncol = n0 + wc + nj * 16 + fr;
            const int h = ncol >> 8, m = ncol & 3;   // m = fr&3 (bases are multiples of 4)
            const float c0 = Ish[h * 16 + (m ^ 0) * 4 + m];
            const float c1 = Ish[h * 16 + (m ^ 1) * 4 + m];
            const float c2 = Ish[h * 16 + (m ^ 2) * 4 + m];
            const float c3 = Ish[h * 16 + (m ^ 3) * 4 + m];
            const float bn = bias[ncol];
            #pragma unroll
            for (int mi = 0; mi < 4; ++mi) {
                #pragma unroll
                for (int j = 0; j < 4; ++j) {
                    float y = acc[mi][nj][j] + bn;
                    float x1 = __shfl_xor(y, 1);
                    float x2 = __shfl_xor(y, 2);
                    float x3 = __shfl_xor(y, 3);
                    float s = y * c0 + x1 * c1 + x2 * c2 + x3 * c3;
                    float zv = (y + camp * s) * qs;
                    int mr = m0 + wr + mi * 16 + fg * 4 + j;
                    Yb[((size_t)z * M + mr) * N + ncol] = f2bf(zv);
                }
            }
        }
    } else {
        #pragma unroll
        for (int nj = 0; nj < 4; ++nj) {
            const int ncol = n0 + wc + nj * 16 + fr;
            const float bn = b0[ncol];
            #pragma unroll
            for (int mi = 0; mi < 4; ++mi) {
                #pragma unroll
                for (int j = 0; j < 4; ++j) {
                    int mr = m0 + wr + mi * 16 + fg * 4 + j;
                    Cf[(size_t)mr * N + ncol] = acc[mi][nj][j] + bn;
                }
            }
        }
    }
}

// ---------------------------------------------------------------- repack: y[3][2048][4096] -> att_in[3][128][1024][64]
__global__ __launch_bounds__(256) void repack_fwd(const u16* __restrict__ Y, u16* __restrict__ Ai) {
    const int bid = blockIdx.x;
    const int st = bid & 15, h = (bid >> 4) & 15, b = (bid >> 8) & 1, p = bid >> 9;
    const int tid = threadIdx.x;
    __shared__ u16 T[64][264];
    const int s0 = st * 64;
    {
        const int sr = tid >> 2, q4 = tid & 3;
        const u16* src = Y + ((size_t)p * 2048 + b * 1024 + s0 + sr) * 4096 + h * 256 + q4 * 64;
        #pragma unroll
        for (int ji = 0; ji < 8; ++ji)
            *(uint4*)&T[sr][q4 * 64 + ji * 8] = *(const uint4*)(src + ji * 8);
    }
    __syncthreads();
    {
        const int s = tid & 63, wv = tid >> 6;
        #pragma unroll
        for (int m = 0; m < 4; ++m) {
            u16* dst = Ai + ((size_t)p * 128 + ((b * 16 + h) * 4 + m)) * 65536 + (size_t)(s0 + s) * 64;
            #pragma unroll
            for (int db = 0; db < 2; ++db) {
                int d0 = wv * 16 + db * 8;
                uint4 o;
                o.x = (u32)T[s][(d0 + 0) * 4 + m] | ((u32)T[s][(d0 + 1) * 4 + m] << 16);
                o.y = (u32)T[s][(d0 + 2) * 4 + m] | ((u32)T[s][(d0 + 3) * 4 + m] << 16);
                o.z = (u32)T[s][(d0 + 4) * 4 + m] | ((u32)T[s][(d0 + 5) * 4 + m] << 16);
                o.w = (u32)T[s][(d0 + 6) * 4 + m] | ((u32)T[s][(d0 + 7) * 4 + m] << 16);
                *(uint4*)(dst + d0) = o;
            }
        }
    }
}

// ---------------------------------------------------------------- repack back: att_out[128][1024][64] -> att_nat[2048][4096]
__global__ __launch_bounds__(256) void repack_back(const u16* __restrict__ Ao, u16* __restrict__ An) {
    const int bid = blockIdx.x;
    const int st = bid & 15, h = (bid >> 4) & 15, b = bid >> 8;
    const int tid = threadIdx.x;
    __shared__ u16 T[64][264];
    const int s0 = st * 64;
    {
        const int sr = tid >> 2, q4 = tid & 3;
        #pragma unroll
        for (int m = 0; m < 4; ++m) {
            const u16* src = Ao + (size_t)((b * 16 + h) * 4 + m) * 65536 + (size_t)(s0 + sr) * 64 + q4 * 16;
            #pragma unroll
            for (int db = 0; db < 2; ++db) {
                uint4 vv = *(const uint4*)(src + db * 8);
                const u16* pv = (const u16*)&vv;
                #pragma unroll
                for (int j = 0; j < 8; ++j)
                    T[sr][(q4 * 16 + db * 8 + j) * 4 + m] = pv[j];
            }
        }
    }
    __syncthreads();
    {
        const int sr = tid >> 2, q4 = tid & 3;
        u16* dst = An + (size_t)(b * 1024 + s0 + sr) * 4096 + h * 256 + q4 * 64;
        #pragma unroll
        for (int ji = 0; ji < 8; ++ji)
            *(uint4*)(dst + ji * 8) = *(const uint4*)&T[sr][q4 * 64 + ji * 8];
    }
}

// ---------------------------------------------------------------- flash attention: 128 problems, S=1024, dk=64
// Qa/Ka/Va/Oa: [128][1024][64] bf16 (Q pre-scaled by 1/8)
// 4 waves/block, wave w owns q-rows [w*16, w*16+16). 72-padded LDS rows ->
// dword row-stride 36 === 4 (mod 32) -> 2-way frag-read aliasing (free, m136).
__global__ __launch_bounds__(256) void attn_fwd(const u16* __restrict__ Qa,
                                                const u16* __restrict__ Ka,
                                                const u16* __restrict__ Va,
                                                u16* __restrict__ Oa) {
    // T1 chunked XCD swizzle: all 16 q-tiles of one problem land on one XCD
    // (2048 blocks, 2048 % 8 == 0 -> bijective).
    const int orig = blockIdx.x;
    const int wgid = (orig & 7) * 256 + (orig >> 3);
    const int p = wgid >> 4, qt = wgid & 15;
    const int tid = threadIdx.x, l = tid & 63, w = tid >> 6;
    const int fr = l & 15, fg = l >> 4;
    __shared__ u16 Qs[64][72];
    __shared__ u16 Ks[64][72];
    __shared__ u16 Vt[64][72];
    __shared__ u16 Ps[4][16][72];
    const size_t pb = (size_t)p * 65536;
    const int q0 = qt * 64;
    {
        const int r = tid >> 2, c = (tid & 3) * 16;
        const uint4* g = (const uint4*)(Qa + pb + (size_t)(q0 + r) * 64 + c);
        uint4 v0 = g[0], v1 = g[1];
        *(uint4*)&Qs[r][c] = v0;
        *(uint4*)&Qs[r][c + 8] = v1;
    }
    __syncthreads();
    bf16x8 aq0 = *(const bf16x8*)&Qs[w * 16 + fr][fg * 8];
    bf16x8 aq1 = *(const bf16x8*)&Qs[w * 16 + fr][32 + fg * 8];
    f32x4 oacc[4] = {};
    float mrow[4] = {-3.0e38f, -3.0e38f, -3.0e38f, -3.0e38f};
    float lrow[4] = {};
    const float L2E = 1.44269504088896f;

    for (int t = 0; t < 16; ++t) {
        const int k0 = t * 64;
        {
            const int r = tid >> 2, c = (tid & 3) * 16;
            const uint4* gk = (const uint4*)(Ka + pb + (size_t)(k0 + r) * 64 + c);
            uint4 ka = gk[0], kb2 = gk[1];
            *(uint4*)&Ks[r][c] = ka;
            *(uint4*)&Ks[r][c + 8] = kb2;
            const uint4* gv = (const uint4*)(Va + pb + (size_t)(k0 + r) * 64 + c);
            uint4 va = gv[0], vb = gv[1];
            const u16* pv0 = (const u16*)&va;
            const u16* pv1 = (const u16*)&vb;
            #pragma unroll
            for (int j = 0; j < 8; ++j) Vt[c + j][r] = pv0[j];
            #pragma unroll
            for (int j = 0; j < 8; ++j) Vt[c + 8 + j][r] = pv1[j];
        }
        __syncthreads();

        f32x4 sa[4] = {};
        __builtin_amdgcn_s_setprio(1);   // T5: favor MFMA wave vs co-resident blocks
        #pragma unroll
        for (int nj = 0; nj < 4; ++nj) {
            bf16x8 kf = *(const bf16x8*)&Ks[nj * 16 + fr][fg * 8];
            sa[nj] = __builtin_amdgcn_mfma_f32_16x16x32_bf16(aq0, kf, sa[nj], 0, 0, 0);
        }
        #pragma unroll
        for (int nj = 0; nj < 4; ++nj) {
            bf16x8 kf = *(const bf16x8*)&Ks[nj * 16 + fr][32 + fg * 8];
            sa[nj] = __builtin_amdgcn_mfma_f32_16x16x32_bf16(aq1, kf, sa[nj], 0, 0, 0);
        }
        __builtin_amdgcn_s_setprio(0);

        float tm[4], mn[4], scl[4], rs[4];
        #pragma unroll
        for (int j = 0; j < 4; ++j)
            tm[j] = fmaxf(fmaxf(sa[0][j], sa[1][j]), fmaxf(sa[2][j], sa[3][j]));
        #pragma unroll
        for (int off = 1; off < 16; off <<= 1)
            #pragma unroll
            for (int j = 0; j < 4; ++j) tm[j] = fmaxf(tm[j], __shfl_xor(tm[j], off));
        #pragma unroll
        for (int j = 0; j < 4; ++j) {
            mn[j] = fmaxf(mrow[j], tm[j]);
            scl[j] = exp2f((mrow[j] - mn[j]) * L2E);
            rs[j] = 0.0f;
        }
        #pragma unroll
        for (int nj = 0; nj < 4; ++nj) {
            #pragma unroll
            for (int j = 0; j < 4; ++j) {
                float pv = exp2f((sa[nj][j] - mn[j]) * L2E);
                rs[j] += pv;
                Ps[w][fg * 4 + j][nj * 16 + fr] = f2bf(pv);
            }
        }
        #pragma unroll
        for (int off = 1; off < 16; off <<= 1)
            #pragma unroll
            for (int j = 0; j < 4; ++j) rs[j] += __shfl_xor(rs[j], off);
        #pragma unroll
        for (int j = 0; j < 4; ++j) {
            lrow[j] = lrow[j] * scl[j] + rs[j];
            mrow[j] = mn[j];
        }
        #pragma unroll
        for (int nd = 0; nd < 4; ++nd)
            #pragma unroll
            for (int j = 0; j < 4; ++j) oacc[nd][j] *= scl[j];

        {
            bf16x8 pa0 = *(const bf16x8*)&Ps[w][fr][fg * 8];
            bf16x8 pa1 = *(const bf16x8*)&Ps[w][fr][32 + fg * 8];
            __builtin_amdgcn_s_setprio(1);
            #pragma unroll
            for (int nd = 0; nd < 4; ++nd) {
                bf16x8 vf = *(const bf16x8*)&Vt[nd * 16 + fr][fg * 8];
                oacc[nd] = __builtin_amdgcn_mfma_f32_16x16x32_bf16(pa0, vf, oacc[nd], 0, 0, 0);
            }
            #pragma unroll
            for (int nd = 0; nd < 4; ++nd) {
                bf16x8 vf = *(const bf16x8*)&Vt[nd * 16 + fr][32 + fg * 8];
                oacc[nd] = __builtin_amdgcn_mfma_f32_16x16x32_bf16(pa1, vf, oacc[nd], 0, 0, 0);
            }
            __builtin_amdgcn_s_setprio(0);
        }
        __syncthreads();
    }

    float inv[4];
    #pragma unroll
    for (int j = 0; j < 4; ++j) inv[j] = 1.0f / lrow[j];
    #pragma unroll
    for (int nd = 0; nd < 4; ++nd)
        #pragma unroll
        for (int j = 0; j < 4; ++j)
            Oa[pb + (size_t)(q0 + w * 16 + fg * 4 + j) * 64 + nd * 16 + fr] =
                f2bf(oacc[nd][j] * inv[j]);
}

// ---------------------------------------------------------------- launch
extern "C" void kernel_launch(void* const* d_in, const int* in_sizes, int n_in,
                              void* d_out, int out_size, void* d_ws, size_t ws_size,
                              hipStream_t stream) {
    const float* q      = (const float*)d_in[0];
    const float* k      = (const float*)d_in[1];
    const float* v      = (const float*)d_in[2];
    const float* Wq     = (const float*)d_in[3];
    const float* bq     = (const float*)d_in[4];
    const float* Wk     = (const float*)d_in[5];
    const float* bk     = (const float*)d_in[6];
    const float* Wv     = (const float*)d_in[7];
    const float* bv     = (const float*)d_in[8];
    const float* interf = (const float*)d_in[9];
    const float* amp    = (const float*)d_in[10];
    const float* Wo     = (const float*)d_in[11];
    const float* bo     = (const float*)d_in[12];
    (void)in_sizes; (void)n_in; (void)out_size; (void)ws_size;

    char* ws = (char*)d_ws;
    // workspace layout (peak 201,326,592 B = 192 MiB):
    //   Wbf [3][4096][4096] bf16 @ 0          (100,663,296 B)
    //        slot 0 reused for Wo after the proj GEMM (Wq_bf16 dead by then)
    //   Xbf [3][2048][4096] bf16 @ 100663296  (50,331,648 B)  -- reused as ATi
    //   Ybf [3][2048][4096] bf16 @ 150994944  (50,331,648 B)  -- reused as ATo+ATn
    u16* Wbf = (u16*)ws;
    u16* Xbf = (u16*)(ws + 100663296);
    u16* Ybf = (u16*)(ws + 150994944);
    u16* ATi = Xbf;                       // [3][128][1024][64]
    u16* ATo = (u16*)(ws + 150994944);    // [128][1024][64]   (16,777,216 B)
    u16* ATn = (u16*)(ws + 167772160);    // [2048][4096]      (16,777,216 B)

    const size_t WE = 16777216;  // elements per weight matrix
    const size_t XE = 8388608;   // elements per activation tensor

    cast_f32_bf16<<<2048, 256, 0, stream>>>(Wq, Wbf + 0 * WE, (int)(WE / 8));
    cast_f32_bf16<<<2048, 256, 0, stream>>>(Wk, Wbf + 1 * WE, (int)(WE / 8));
    cast_f32_bf16<<<2048, 256, 0, stream>>>(Wv, Wbf + 2 * WE, (int)(WE / 8));
    cast_f32_bf16<<<2048, 256, 0, stream>>>(q, Xbf + 0 * XE, (int)(XE / 8));
    cast_f32_bf16<<<2048, 256, 0, stream>>>(k, Xbf + 1 * XE, (int)(XE / 8));
    cast_f32_bf16<<<2048, 256, 0, stream>>>(v, Xbf + 2 * XE, (int)(XE / 8));

    gemm_bt<true><<<dim3(32, 16, 3), 256, 0, stream>>>(Xbf, Wbf, bq, bk, bv, interf, amp,
                                                       Ybf, nullptr);

    // Wq_bf16 (slot 0) is dead now; cast Wo into it for the final GEMM.
    cast_f32_bf16<<<2048, 256, 0, stream>>>(Wo, Wbf + 0 * WE, (int)(WE / 8));

    repack_fwd<<<1536, 256, 0, stream>>>(Ybf, ATi);

    attn_fwd<<<dim3(2048), 256, 0, stream>>>(ATi, ATi + XE, ATi + 2 * XE, ATo);

    repack_back<<<512, 256, 0, stream>>>(ATo, ATn);

    gemm_bt<false><<<dim3(32, 16, 1), 256, 0, stream>>>(ATn, Wbf + 0 * WE, bo, nullptr, nullptr,
                                                        nullptr, nullptr, nullptr, (float*)d_out);
}

// Round 4
// 872.280 us; speedup vs baseline: 1.1330x; 1.1330x over previous
//
#include <hip/hip_runtime.h>
#include <hip/hip_bf16.h>

typedef unsigned short u16;
typedef unsigned int u32;
typedef __attribute__((ext_vector_type(8))) short bf16x8;
typedef __attribute__((ext_vector_type(4))) float f32x4;

// ---------------------------------------------------------------- helpers
__device__ __forceinline__ u16 f2bf(float f) {
    u32 u = __float_as_uint(f);
    u += 0x7FFFu + ((u >> 16) & 1u);   // RNE
    return (u16)(u >> 16);
}
__device__ __forceinline__ u32 pack2(float a, float b) {
    return (u32)f2bf(a) | ((u32)f2bf(b) << 16);
}

#define GLDS16(gp, lp)                                                          \
    __builtin_amdgcn_global_load_lds(                                           \
        (const __attribute__((address_space(1))) void*)(gp),                    \
        (__attribute__((address_space(3))) void*)(lp), 16, 0, 0)

#define FENCE asm volatile("" ::: "memory")
#define BAR()  do { FENCE; __builtin_amdgcn_s_barrier(); FENCE; } while (0)
#define VM2()  asm volatile("s_waitcnt vmcnt(2)" ::: "memory")
#define LG0()  do { asm volatile("s_waitcnt lgkmcnt(0)" ::: "memory");          \
                    __builtin_amdgcn_sched_barrier(0); } while (0)

// ---------------------------------------------------------------- cast fp32 -> bf16
__global__ __launch_bounds__(256) void cast_f32_bf16(const float* __restrict__ src,
                                                     u16* __restrict__ dst, int n8) {
    int stride = gridDim.x * blockDim.x;
    for (int i = blockIdx.x * blockDim.x + threadIdx.x; i < n8; i += stride) {
        const float4* sp = (const float4*)src + (size_t)i * 2;
        float4 a = sp[0], b = sp[1];
        uint4 o;
        o.x = pack2(a.x, a.y);
        o.y = pack2(a.z, a.w);
        o.z = pack2(b.x, b.y);
        o.w = pack2(b.z, b.w);
        ((uint4*)dst)[i] = o;
    }
}

// ---------------------------------------------------------------- proj GEMM, 256x256 8-phase
// C = A*B^T (+bias +interference mix, bf16 out). A:[z][2048][4096], B:[z][4096][4096].
// 512 thr = 8 waves (2 wrow x 4 wcol); per K-tile (BK=64) 4 phases, one C-quadrant each.
// Stage slots: P1:Ah1(t) P2:Ah0(t+1) P3:Bh0(t+1) P4:Bh1(t+1); vmcnt(2) at P1/P2/P4 end
// guarantees each half retires one barrier before its first ds_read (counted, never 0).
// LDS reads swizzled byte^=(row&7)<<4; inverse applied to per-lane GLOBAL source so
// global_load_lds dests stay linear (rule #21).
__global__ __launch_bounds__(512, 1) void gemm8_proj(
    const u16* __restrict__ Ab, const u16* __restrict__ Bb,
    const float* __restrict__ b0, const float* __restrict__ b1, const float* __restrict__ b2,
    const float* __restrict__ interf, const float* __restrict__ amp,
    u16* __restrict__ Yb) {
    constexpr int K = 4096, NT = 64;
    __shared__ u16 As[2][16384];
    __shared__ u16 Bs[2][16384];
    __shared__ float Ish[256];
    const int tid = threadIdx.x;
    if (tid < 256) Ish[tid] = interf[tid];
    const int l = tid & 63, w = tid >> 6;
    const int wrow = w >> 2, wcol = w & 3;
    const int fr = l & 15, fg = l >> 4;
    const int z = blockIdx.z;
    const int n0 = blockIdx.x * 256, m0 = blockIdx.y * 256;
    const u16* A = Ab + (size_t)z * 2048 * K;
    const u16* B = Bb + (size_t)z * 4096 * K;

    // staging constants: lane l stages LDS halfword offset (lane*8) in its wave's 512-elem
    // chunk; source col pre-inverse-swizzled so swizzled reads see A[row][k] in order.
    const int lr = l >> 3;                     // row within the wave's 8-row chunk
    const int sc = ((l & 7) ^ lr) * 8;         // inverse-swizzled source col (elems)
    const size_t aBase = (size_t)(m0 + w * 8 + lr) * K + sc;
    const size_t bBase = (size_t)(n0 + w * 8 + lr) * K + sc;
    const int ldsLane = w * 512 + l * 8;

#define STG_A(h, tt) do { int bsel_ = ((tt) & 1); int ts_ = (tt) < NT ? (tt) : NT - 1;        \
    GLDS16(A + aBase + (size_t)((h) * 128) * K + ts_ * 64, &As[bsel_][(h) * 8192 + ldsLane]); \
    GLDS16(A + aBase + (size_t)((h) * 128 + 64) * K + ts_ * 64,                               \
           &As[bsel_][(h) * 8192 + 4096 + ldsLane]); } while (0)
#define STG_B(h, tt) do { int bsel_ = ((tt) & 1); int ts_ = (tt) < NT ? (tt) : NT - 1;        \
    GLDS16(B + bBase + (size_t)((h) * 128) * K + ts_ * 64, &Bs[bsel_][(h) * 8192 + ldsLane]); \
    GLDS16(B + bBase + (size_t)((h) * 128 + 64) * K + ts_ * 64,                               \
           &Bs[bsel_][(h) * 8192 + 4096 + ldsLane]); } while (0)

    // swizzled read column offsets (elems): (kk*32 + fg*8) ^ ((fr&7)*8)
    const int kx = (fr & 7) * 8;
    const int ca = (fg * 8) ^ kx;
    const int cb = (32 + fg * 8) ^ kx;
    const int aR = (wrow * 64 + fr) * 64;      // qr=0 row base (elems)
    const int bR = (wcol * 32 + fr) * 64;      // qc=0 row base (elems)

    f32x4 acc[2][2][4][2] = {};
    bf16x8 a[4][2], q0b[2][2], q1b[2][2];

    // prologue: Ah0(0), Bh0(0), Bh1(0); retire first two halves, keep Bh1 in flight
    STG_A(0, 0);
    STG_B(0, 0);
    STG_B(1, 0);
    VM2();
    BAR();

    for (int t = 0; t < NT; ++t) {
        const int bs = t & 1;
        const u16* Ac = As[bs];
        const u16* Bc = Bs[bs];
        // ---- P1: read A-qr0 + B-qc0; stage Ah1(t); MFMA Q(0,0)
        #pragma unroll
        for (int mf = 0; mf < 4; ++mf) {
            a[mf][0] = *(const bf16x8*)&Ac[aR + mf * 1024 + ca];
            a[mf][1] = *(const bf16x8*)&Ac[aR + mf * 1024 + cb];
        }
        #pragma unroll
        for (int nf = 0; nf < 2; ++nf) {
            q0b[nf][0] = *(const bf16x8*)&Bc[bR + nf * 1024 + ca];
            q0b[nf][1] = *(const bf16x8*)&Bc[bR + nf * 1024 + cb];
        }
        STG_A(1, t);
        BAR();
        LG0();
        __builtin_amdgcn_s_setprio(1);
        #pragma unroll
        for (int mf = 0; mf < 4; ++mf)
            #pragma unroll
            for (int nf = 0; nf < 2; ++nf)
                #pragma unroll
                for (int kk = 0; kk < 2; ++kk)
                    acc[0][0][mf][nf] = __builtin_amdgcn_mfma_f32_16x16x32_bf16(
                        a[mf][kk], q0b[nf][kk], acc[0][0][mf][nf], 0, 0, 0);
        __builtin_amdgcn_s_setprio(0);
        VM2();
        BAR();
        // ---- P2: read B-qc1; stage Ah0(t+1); MFMA Q(0,1)
        #pragma unroll
        for (int nf = 0; nf < 2; ++nf) {
            q1b[nf][0] = *(const bf16x8*)&Bc[bR + 8192 + nf * 1024 + ca];
            q1b[nf][1] = *(const bf16x8*)&Bc[bR + 8192 + nf * 1024 + cb];
        }
        STG_A(0, t + 1);
        BAR();
        LG0();
        __builtin_amdgcn_s_setprio(1);
        #pragma unroll
        for (int mf = 0; mf < 4; ++mf)
            #pragma unroll
            for (int nf = 0; nf < 2; ++nf)
                #pragma unroll
                for (int kk = 0; kk < 2; ++kk)
                    acc[0][1][mf][nf] = __builtin_amdgcn_mfma_f32_16x16x32_bf16(
                        a[mf][kk], q1b[nf][kk], acc[0][1][mf][nf], 0, 0, 0);
        __builtin_amdgcn_s_setprio(0);
        VM2();
        BAR();
        // ---- P3: read A-qr1; stage Bh0(t+1); MFMA Q(1,1)
        #pragma unroll
        for (int mf = 0; mf < 4; ++mf) {
            a[mf][0] = *(const bf16x8*)&Ac[aR + 8192 + mf * 1024 + ca];
            a[mf][1] = *(const bf16x8*)&Ac[aR + 8192 + mf * 1024 + cb];
        }
        STG_B(0, t + 1);
        BAR();
        LG0();
        __builtin_amdgcn_s_setprio(1);
        #pragma unroll
        for (int mf = 0; mf < 4; ++mf)
            #pragma unroll
            for (int nf = 0; nf < 2; ++nf)
                #pragma unroll
                for (int kk = 0; kk < 2; ++kk)
                    acc[1][1][mf][nf] = __builtin_amdgcn_mfma_f32_16x16x32_bf16(
                        a[mf][kk], q1b[nf][kk], acc[1][1][mf][nf], 0, 0, 0);
        __builtin_amdgcn_s_setprio(0);
        BAR();
        // ---- P4: (regs only); stage Bh1(t+1); MFMA Q(1,0)
        STG_B(1, t + 1);
        BAR();
        __builtin_amdgcn_s_setprio(1);
        #pragma unroll
        for (int mf = 0; mf < 4; ++mf)
            #pragma unroll
            for (int nf = 0; nf < 2; ++nf)
                #pragma unroll
                for (int kk = 0; kk < 2; ++kk)
                    acc[1][0][mf][nf] = __builtin_amdgcn_mfma_f32_16x16x32_bf16(
                        a[mf][kk], q0b[nf][kk], acc[1][0][mf][nf], 0, 0, 0);
        __builtin_amdgcn_s_setprio(0);
        VM2();
        BAR();
    }
#undef STG_A
#undef STG_B

    // epilogue: bias + interference mix (shfl_xor over m = fr&3), fold 0.125 into Q
    const float camp = 0.1f * amp[0];
    const float* bias = (z == 0) ? b0 : (z == 1) ? b1 : b2;
    const float qs = (z == 0) ? 0.125f : 1.0f;
    #pragma unroll
    for (int qc = 0; qc < 2; ++qc)
        #pragma unroll
        for (int nf = 0; nf < 2; ++nf) {
            const int ncol = n0 + qc * 128 + wcol * 32 + nf * 16 + fr;
            const int hh = ncol >> 8, mm = fr & 3;
            const float i0 = Ish[hh * 16 + (mm ^ 0) * 4 + mm];
            const float i1 = Ish[hh * 16 + (mm ^ 1) * 4 + mm];
            const float i2 = Ish[hh * 16 + (mm ^ 2) * 4 + mm];
            const float i3 = Ish[hh * 16 + (mm ^ 3) * 4 + mm];
            const float bn = bias[ncol];
            #pragma unroll
            for (int qr = 0; qr < 2; ++qr)
                #pragma unroll
                for (int mf = 0; mf < 4; ++mf)
                    #pragma unroll
                    for (int j = 0; j < 4; ++j) {
                        float y = acc[qr][qc][mf][nf][j] + bn;
                        float x1 = __shfl_xor(y, 1);
                        float x2 = __shfl_xor(y, 2);
                        float x3 = __shfl_xor(y, 3);
                        float s = y * i0 + x1 * i1 + x2 * i2 + x3 * i3;
                        float zv = (y + camp * s) * qs;
                        int mr = m0 + qr * 128 + wrow * 64 + mf * 16 + fg * 4 + j;
                        Yb[((size_t)z * 2048 + mr) * 4096 + ncol] = f2bf(zv);
                    }
        }
}

// ---------------------------------------------------------------- final GEMM (m97 128x128, validated r3)
__global__ __launch_bounds__(256) void gemm_bt_f32(
    const u16* __restrict__ Ab, const u16* __restrict__ Bb,
    const float* __restrict__ b0, float* __restrict__ Cf) {
    constexpr int K = 4096, N = 4096;
    const int tid = threadIdx.x;
    const int l = tid & 63, w = tid >> 6;
    const int n0 = blockIdx.x * 128, m0 = blockIdx.y * 128;
    const u16* A = Ab;
    const u16* B = Bb;

    __shared__ u16 As[128 * 64];
    __shared__ u16 Bs[128 * 64];

    const int wr = (w >> 1) * 64, wc = (w & 1) * 64;
    const int fr = l & 15, fg = l >> 4;

    f32x4 acc[4][4] = {};

    int srow[4], scol[4], soff[4];
    #pragma unroll
    for (int r = 0; r < 4; ++r) {
        int e = (r * 4 + w) * 512 + l * 8;
        soff[r] = e;
        srow[r] = e >> 6;
        scol[r] = e & 63;
    }

    for (int kt = 0; kt < K; kt += 64) {
        #pragma unroll
        for (int r = 0; r < 4; ++r) {
            GLDS16(A + (size_t)(m0 + srow[r]) * K + kt + scol[r], As + soff[r]);
            GLDS16(B + (size_t)(n0 + srow[r]) * K + kt + scol[r], Bs + soff[r]);
        }
        __syncthreads();
        #pragma unroll
        for (int kb = 0; kb < 2; ++kb) {
            bf16x8 af[4], bfr[4];
            #pragma unroll
            for (int mi = 0; mi < 4; ++mi)
                af[mi] = *(const bf16x8*)&As[(wr + mi * 16 + fr) * 64 + kb * 32 + fg * 8];
            #pragma unroll
            for (int nj = 0; nj < 4; ++nj)
                bfr[nj] = *(const bf16x8*)&Bs[(wc + nj * 16 + fr) * 64 + kb * 32 + fg * 8];
            #pragma unroll
            for (int mi = 0; mi < 4; ++mi)
                #pragma unroll
                for (int nj = 0; nj < 4; ++nj)
                    acc[mi][nj] = __builtin_amdgcn_mfma_f32_16x16x32_bf16(af[mi], bfr[nj],
                                                                          acc[mi][nj], 0, 0, 0);
        }
        __syncthreads();
    }

    #pragma unroll
    for (int nj = 0; nj < 4; ++nj) {
        const int ncol = n0 + wc + nj * 16 + fr;
        const float bn = b0[ncol];
        #pragma unroll
        for (int mi = 0; mi < 4; ++mi) {
            #pragma unroll
            for (int j = 0; j < 4; ++j) {
                int mr = m0 + wr + mi * 16 + fg * 4 + j;
                Cf[(size_t)mr * N + ncol] = acc[mi][nj][j] + bn;
            }
        }
    }
}

// ---------------------------------------------------------------- repack: y[3][2048][4096] -> att_in[3][128][1024][64]
__global__ __launch_bounds__(256) void repack_fwd(const u16* __restrict__ Y, u16* __restrict__ Ai) {
    const int bid = blockIdx.x;
    const int st = bid & 15, h = (bid >> 4) & 15, b = (bid >> 8) & 1, p = bid >> 9;
    const int tid = threadIdx.x;
    __shared__ u16 T[64][264];
    const int s0 = st * 64;
    {
        const int sr = tid >> 2, q4 = tid & 3;
        const u16* src = Y + ((size_t)p * 2048 + b * 1024 + s0 + sr) * 4096 + h * 256 + q4 * 64;
        #pragma unroll
        for (int ji = 0; ji < 8; ++ji)
            *(uint4*)&T[sr][q4 * 64 + ji * 8] = *(const uint4*)(src + ji * 8);
    }
    __syncthreads();
    {
        const int s = tid & 63, wv = tid >> 6;
        #pragma unroll
        for (int m = 0; m < 4; ++m) {
            u16* dst = Ai + ((size_t)p * 128 + ((b * 16 + h) * 4 + m)) * 65536 + (size_t)(s0 + s) * 64;
            #pragma unroll
            for (int db = 0; db < 2; ++db) {
                int d0 = wv * 16 + db * 8;
                uint4 o;
                o.x = (u32)T[s][(d0 + 0) * 4 + m] | ((u32)T[s][(d0 + 1) * 4 + m] << 16);
                o.y = (u32)T[s][(d0 + 2) * 4 + m] | ((u32)T[s][(d0 + 3) * 4 + m] << 16);
                o.z = (u32)T[s][(d0 + 4) * 4 + m] | ((u32)T[s][(d0 + 5) * 4 + m] << 16);
                o.w = (u32)T[s][(d0 + 6) * 4 + m] | ((u32)T[s][(d0 + 7) * 4 + m] << 16);
                *(uint4*)(dst + d0) = o;
            }
        }
    }
}

// ---------------------------------------------------------------- repack back: att_out[128][1024][64] -> att_nat[2048][4096]
__global__ __launch_bounds__(256) void repack_back(const u16* __restrict__ Ao, u16* __restrict__ An) {
    const int bid = blockIdx.x;
    const int st = bid & 15, h = (bid >> 4) & 15, b = bid >> 8;
    const int tid = threadIdx.x;
    __shared__ u16 T[64][264];
    const int s0 = st * 64;
    {
        const int sr = tid >> 2, q4 = tid & 3;
        #pragma unroll
        for (int m = 0; m < 4; ++m) {
            const u16* src = Ao + (size_t)((b * 16 + h) * 4 + m) * 65536 + (size_t)(s0 + sr) * 64 + q4 * 16;
            #pragma unroll
            for (int db = 0; db < 2; ++db) {
                uint4 vv = *(const uint4*)(src + db * 8);
                const u16* pv = (const u16*)&vv;
                #pragma unroll
                for (int j = 0; j < 8; ++j)
                    T[sr][(q4 * 16 + db * 8 + j) * 4 + m] = pv[j];
            }
        }
    }
    __syncthreads();
    {
        const int sr = tid >> 2, q4 = tid & 3;
        u16* dst = An + (size_t)(b * 1024 + s0 + sr) * 4096 + h * 256 + q4 * 64;
        #pragma unroll
        for (int ji = 0; ji < 8; ++ji)
            *(uint4*)(dst + ji * 8) = *(const uint4*)&T[sr][q4 * 64 + ji * 8];
    }
}

// ---------------------------------------------------------------- flash attention: 128 problems, S=1024, dk=64
__global__ __launch_bounds__(256) void attn_fwd(const u16* __restrict__ Qa,
                                                const u16* __restrict__ Ka,
                                                const u16* __restrict__ Va,
                                                u16* __restrict__ Oa) {
    const int orig = blockIdx.x;
    const int wgid = (orig & 7) * 256 + (orig >> 3);
    const int p = wgid >> 4, qt = wgid & 15;
    const int tid = threadIdx.x, l = tid & 63, w = tid >> 6;
    const int fr = l & 15, fg = l >> 4;
    __shared__ u16 Qs[64][72];
    __shared__ u16 Ks[64][72];
    __shared__ u16 Vt[64][72];
    __shared__ u16 Ps[4][16][72];
    const size_t pb = (size_t)p * 65536;
    const int q0 = qt * 64;
    {
        const int r = tid >> 2, c = (tid & 3) * 16;
        const uint4* g = (const uint4*)(Qa + pb + (size_t)(q0 + r) * 64 + c);
        uint4 v0 = g[0], v1 = g[1];
        *(uint4*)&Qs[r][c] = v0;
        *(uint4*)&Qs[r][c + 8] = v1;
    }
    __syncthreads();
    bf16x8 aq0 = *(const bf16x8*)&Qs[w * 16 + fr][fg * 8];
    bf16x8 aq1 = *(const bf16x8*)&Qs[w * 16 + fr][32 + fg * 8];
    f32x4 oacc[4] = {};
    float mrow[4] = {-3.0e38f, -3.0e38f, -3.0e38f, -3.0e38f};
    float lrow[4] = {};
    const float L2E = 1.44269504088896f;

    for (int t = 0; t < 16; ++t) {
        const int k0 = t * 64;
        {
            const int r = tid >> 2, c = (tid & 3) * 16;
            const uint4* gk = (const uint4*)(Ka + pb + (size_t)(k0 + r) * 64 + c);
            uint4 ka = gk[0], kb2 = gk[1];
            *(uint4*)&Ks[r][c] = ka;
            *(uint4*)&Ks[r][c + 8] = kb2;
            const uint4* gv = (const uint4*)(Va + pb + (size_t)(k0 + r) * 64 + c);
            uint4 va = gv[0], vb = gv[1];
            const u16* pv0 = (const u16*)&va;
            const u16* pv1 = (const u16*)&vb;
            #pragma unroll
            for (int j = 0; j < 8; ++j) Vt[c + j][r] = pv0[j];
            #pragma unroll
            for (int j = 0; j < 8; ++j) Vt[c + 8 + j][r] = pv1[j];
        }
        __syncthreads();

        f32x4 sa[4] = {};
        __builtin_amdgcn_s_setprio(1);
        #pragma unroll
        for (int nj = 0; nj < 4; ++nj) {
            bf16x8 kf = *(const bf16x8*)&Ks[nj * 16 + fr][fg * 8];
            sa[nj] = __builtin_amdgcn_mfma_f32_16x16x32_bf16(aq0, kf, sa[nj], 0, 0, 0);
        }
        #pragma unroll
        for (int nj = 0; nj < 4; ++nj) {
            bf16x8 kf = *(const bf16x8*)&Ks[nj * 16 + fr][32 + fg * 8];
            sa[nj] = __builtin_amdgcn_mfma_f32_16x16x32_bf16(aq1, kf, sa[nj], 0, 0, 0);
        }
        __builtin_amdgcn_s_setprio(0);

        float tm[4], mn[4], scl[4], rs[4];
        #pragma unroll
        for (int j = 0; j < 4; ++j)
            tm[j] = fmaxf(fmaxf(sa[0][j], sa[1][j]), fmaxf(sa[2][j], sa[3][j]));
        #pragma unroll
        for (int off = 1; off < 16; off <<= 1)
            #pragma unroll
            for (int j = 0; j < 4; ++j) tm[j] = fmaxf(tm[j], __shfl_xor(tm[j], off));
        #pragma unroll
        for (int j = 0; j < 4; ++j) {
            mn[j] = fmaxf(mrow[j], tm[j]);
            scl[j] = exp2f((mrow[j] - mn[j]) * L2E);
            rs[j] = 0.0f;
        }
        #pragma unroll
        for (int nj = 0; nj < 4; ++nj) {
            #pragma unroll
            for (int j = 0; j < 4; ++j) {
                float pv = exp2f((sa[nj][j] - mn[j]) * L2E);
                rs[j] += pv;
                Ps[w][fg * 4 + j][nj * 16 + fr] = f2bf(pv);
            }
        }
        #pragma unroll
        for (int off = 1; off < 16; off <<= 1)
            #pragma unroll
            for (int j = 0; j < 4; ++j) rs[j] += __shfl_xor(rs[j], off);
        #pragma unroll
        for (int j = 0; j < 4; ++j) {
            lrow[j] = lrow[j] * scl[j] + rs[j];
            mrow[j] = mn[j];
        }
        #pragma unroll
        for (int nd = 0; nd < 4; ++nd)
            #pragma unroll
            for (int j = 0; j < 4; ++j) oacc[nd][j] *= scl[j];

        {
            bf16x8 pa0 = *(const bf16x8*)&Ps[w][fr][fg * 8];
            bf16x8 pa1 = *(const bf16x8*)&Ps[w][fr][32 + fg * 8];
            __builtin_amdgcn_s_setprio(1);
            #pragma unroll
            for (int nd = 0; nd < 4; ++nd) {
                bf16x8 vf = *(const bf16x8*)&Vt[nd * 16 + fr][fg * 8];
                oacc[nd] = __builtin_amdgcn_mfma_f32_16x16x32_bf16(pa0, vf, oacc[nd], 0, 0, 0);
            }
            #pragma unroll
            for (int nd = 0; nd < 4; ++nd) {
                bf16x8 vf = *(const bf16x8*)&Vt[nd * 16 + fr][32 + fg * 8];
                oacc[nd] = __builtin_amdgcn_mfma_f32_16x16x32_bf16(pa1, vf, oacc[nd], 0, 0, 0);
            }
            __builtin_amdgcn_s_setprio(0);
        }
        __syncthreads();
    }

    float inv[4];
    #pragma unroll
    for (int j = 0; j < 4; ++j) inv[j] = 1.0f / lrow[j];
    #pragma unroll
    for (int nd = 0; nd < 4; ++nd)
        #pragma unroll
        for (int j = 0; j < 4; ++j)
            Oa[pb + (size_t)(q0 + w * 16 + fg * 4 + j) * 64 + nd * 16 + fr] =
                f2bf(oacc[nd][j] * inv[j]);
}

// ---------------------------------------------------------------- launch
extern "C" void kernel_launch(void* const* d_in, const int* in_sizes, int n_in,
                              void* d_out, int out_size, void* d_ws, size_t ws_size,
                              hipStream_t stream) {
    const float* q      = (const float*)d_in[0];
    const float* k      = (const float*)d_in[1];
    const float* v      = (const float*)d_in[2];
    const float* Wq     = (const float*)d_in[3];
    const float* bq     = (const float*)d_in[4];
    const float* Wk     = (const float*)d_in[5];
    const float* bk     = (const float*)d_in[6];
    const float* Wv     = (const float*)d_in[7];
    const float* bv     = (const float*)d_in[8];
    const float* interf = (const float*)d_in[9];
    const float* amp    = (const float*)d_in[10];
    const float* Wo     = (const float*)d_in[11];
    const float* bo     = (const float*)d_in[12];
    (void)in_sizes; (void)n_in; (void)out_size; (void)ws_size;

    char* ws = (char*)d_ws;
    // workspace layout (peak 192 MiB):
    //   Wbf [3][4096][4096] bf16 @ 0          (slot 0 reused for Wo after proj GEMM)
    //   Xbf [3][2048][4096] bf16 @ 100663296  (reused as ATi)
    //   Ybf [3][2048][4096] bf16 @ 150994944  (reused as ATo+ATn)
    u16* Wbf = (u16*)ws;
    u16* Xbf = (u16*)(ws + 100663296);
    u16* Ybf = (u16*)(ws + 150994944);
    u16* ATi = Xbf;
    u16* ATo = (u16*)(ws + 150994944);
    u16* ATn = (u16*)(ws + 167772160);

    const size_t WE = 16777216;
    const size_t XE = 8388608;

    cast_f32_bf16<<<2048, 256, 0, stream>>>(Wq, Wbf + 0 * WE, (int)(WE / 8));
    cast_f32_bf16<<<2048, 256, 0, stream>>>(Wk, Wbf + 1 * WE, (int)(WE / 8));
    cast_f32_bf16<<<2048, 256, 0, stream>>>(Wv, Wbf + 2 * WE, (int)(WE / 8));
    cast_f32_bf16<<<2048, 256, 0, stream>>>(q, Xbf + 0 * XE, (int)(XE / 8));
    cast_f32_bf16<<<2048, 256, 0, stream>>>(k, Xbf + 1 * XE, (int)(XE / 8));
    cast_f32_bf16<<<2048, 256, 0, stream>>>(v, Xbf + 2 * XE, (int)(XE / 8));

    gemm8_proj<<<dim3(16, 8, 3), 512, 0, stream>>>(Xbf, Wbf, bq, bk, bv, interf, amp, Ybf);

    // Wq_bf16 (slot 0) dead now; cast Wo into it for the final GEMM.
    cast_f32_bf16<<<2048, 256, 0, stream>>>(Wo, Wbf + 0 * WE, (int)(WE / 8));

    repack_fwd<<<1536, 256, 0, stream>>>(Ybf, ATi);

    attn_fwd<<<dim3(2048), 256, 0, stream>>>(ATi, ATi + XE, ATi + 2 * XE, ATo);

    repack_back<<<512, 256, 0, stream>>>(ATo, ATn);

    gemm_bt_f32<<<dim3(32, 16), 256, 0, stream>>>(ATn, Wbf + 0 * WE, bo, (float*)d_out);
}